// Round 4
// baseline (128.834 us; speedup 1.0000x reference)
//
#include <hip/hip_runtime.h>

#define NB 256
#define NJ 24
#define NV 6890
#define WT_LD 6892   // NV padded to multiple of 4 so every wT row is float4-aligned

// ---------------------------------------------------------------------------
// Kernel 0 (optional): transpose lbs weights (V,J) -> (J, V_padded) so the
// vertex-blend kernel can load them as fully-coalesced float4.
// ---------------------------------------------------------------------------
__global__ __launch_bounds__(256) void transpose_w(const float* __restrict__ w,
                                                   float* __restrict__ wT) {
    const int idx = blockIdx.x * 256 + threadIdx.x;
    if (idx >= NV * NJ) return;
    const int v = idx / NJ, j = idx % NJ;
    wT[(size_t)j * WT_LD + v] = w[idx];   // read coalesced; write scattered (tiny: 661 KB)
}

// ---------------------------------------------------------------------------
// Kernel 1: kinematic chain via parallel ancestor doubling.
// One block per batch, 288 threads = 24 joints x 12 matrix elements.
// Max tree depth = 8 -> 4 doubling steps with compile-time ancestor tables.
// ---------------------------------------------------------------------------
__device__ __constant__ int ANC[4][NJ] = {
  {-1, 0, 0, 0, 1, 2, 3, 4, 5, 6, 7, 8, 9, 9, 9,12,13,14,16,17,18,19,20,21},
  {-1,-1,-1,-1, 0, 0, 0, 1, 2, 3, 4, 5, 6, 6, 6, 9, 9, 9,13,14,16,17,18,19},
  {-1,-1,-1,-1,-1,-1,-1,-1,-1,-1, 0, 0, 0, 0, 0, 3, 3, 3, 6, 6, 9, 9,13,14},
  {-1,-1,-1,-1,-1,-1,-1,-1,-1,-1,-1,-1,-1,-1,-1,-1,-1,-1,-1,-1,-1,-1, 0, 0}};

__global__ __launch_bounds__(288) void chain2(
    const float* __restrict__ rot,      // (B,J,3,3)
    const float* __restrict__ joints,   // (B,J,3)
    float* __restrict__ posed_joints,   // (B,J,3)
    float* __restrict__ rel_tf)         // (B,J,4,4)
{
    __shared__ float Jl[NJ * 3];
    __shared__ float MA[NJ * 12];
    __shared__ float MB[NJ * 12];
    const int b = blockIdx.x, tid = threadIdx.x;
    const int j = tid / 12, e = tid % 12, r = e >> 2, c = e & 3;
    constexpr int par[NJ] = {0,0,0,0,1,2,3,4,5,6,7,8,9,9,9,12,13,14,16,17,18,19,20,21};

    if (tid < NJ * 3) Jl[tid] = joints[(size_t)b * NJ * 3 + tid];
    __syncthreads();

    // Build T_local element (r,c) of joint j.
    float tv;
    if (c < 3) {
        tv = rot[(size_t)b * NJ * 9 + j * 9 + r * 3 + c];   // coalesced-ish (monotone)
    } else {
        tv = Jl[j * 3 + r];
        if (j > 0) tv -= Jl[par[j] * 3 + r];
    }
    MA[j * 12 + e] = tv;
    __syncthreads();

    // M_{k+1}[j] = M_k[anc_k[j]] @ M_k[j] (3x4 homogeneous, implicit [0,0,0,1]).
#define DSTEP(SRC, DST, K)                                                 \
    do {                                                                   \
        const int a = ANC[K][j];                                           \
        float nv;                                                          \
        if (a < 0) {                                                       \
            nv = SRC[j * 12 + e];                                          \
        } else {                                                           \
            nv = SRC[a * 12 + r * 4 + 0] * SRC[j * 12 + 0 + c]            \
               + SRC[a * 12 + r * 4 + 1] * SRC[j * 12 + 4 + c]            \
               + SRC[a * 12 + r * 4 + 2] * SRC[j * 12 + 8 + c];           \
            if (c == 3) nv += SRC[a * 12 + r * 4 + 3];                    \
        }                                                                  \
        DST[j * 12 + e] = nv;                                              \
        __syncthreads();                                                   \
    } while (0)

    DSTEP(MA, MB, 0);
    DSTEP(MB, MA, 1);
    DSTEP(MA, MB, 2);
    DSTEP(MB, MA, 3);
    // Final global transforms A are in MA.

    const float aje = MA[j * 12 + e];
    if (c == 3) {
        posed_joints[(size_t)b * NJ * 3 + j * 3 + r] = aje;
        const float tj = MA[j * 12 + r * 4 + 0] * Jl[j * 3 + 0]
                       + MA[j * 12 + r * 4 + 1] * Jl[j * 3 + 1]
                       + MA[j * 12 + r * 4 + 2] * Jl[j * 3 + 2];
        rel_tf[(size_t)b * NJ * 16 + j * 16 + e] = aje - tj;
    } else {
        rel_tf[(size_t)b * NJ * 16 + j * 16 + e] = aje;
    }
    if (tid < NJ * 4) {   // bottom rows [0,0,0,1]
        const int j2 = tid >> 2, c2 = tid & 3;
        rel_tf[(size_t)b * NJ * 16 + j2 * 16 + 12 + c2] = (c2 == 3) ? 1.0f : 0.0f;
    }
}

// ---------------------------------------------------------------------------
// Kernel 2: vertex blend, 4 verts/thread, transforms via uniform (scalar) loads.
// ---------------------------------------------------------------------------
__device__ __forceinline__ float f4c(const float4& q, int l) {
    switch (l) {  // l is a compile-time constant under full unroll
        case 0: return q.x;
        case 1: return q.y;
        case 2: return q.z;
        default: return q.w;
    }
}

template <bool WT>
__global__ __launch_bounds__(256) void lbs2(
    const float* __restrict__ verts,    // (B,V,3)
    const float* __restrict__ wgt,      // (V,J)
    const float* __restrict__ wTp,      // (J, WT_LD) if WT
    const float* __restrict__ rel_tf,   // (B,J,4,4)
    float* __restrict__ out_verts)      // (B,V,3)
{
    const int b = blockIdx.y, tid = threadIdx.x;
    const int v0 = blockIdx.x * 1024 + tid * 4;
    if (v0 >= NV) return;
    const float* __restrict__ Mb = rel_tf + (size_t)b * NJ * 16;  // uniform -> s_load

    float acc[4][12];
#pragma unroll
    for (int v = 0; v < 4; ++v)
#pragma unroll
        for (int q = 0; q < 12; ++q) acc[v][q] = 0.0f;

    if (v0 + 4 <= NV) {
        if (WT) {
#pragma unroll
            for (int jj = 0; jj < NJ; ++jj) {
                const float4 wv = *reinterpret_cast<const float4*>(wTp + (size_t)jj * WT_LD + v0);
                const float4 m0 = *reinterpret_cast<const float4*>(Mb + jj * 16 + 0);
                const float4 m1 = *reinterpret_cast<const float4*>(Mb + jj * 16 + 4);
                const float4 m2 = *reinterpret_cast<const float4*>(Mb + jj * 16 + 8);
                const float m[12] = {m0.x, m0.y, m0.z, m0.w, m1.x, m1.y,
                                     m1.z, m1.w, m2.x, m2.y, m2.z, m2.w};
                const float wl[4] = {wv.x, wv.y, wv.z, wv.w};
#pragma unroll
                for (int v = 0; v < 4; ++v)
#pragma unroll
                    for (int q = 0; q < 12; ++q) acc[v][q] += wl[v] * m[q];
            }
        } else {
#pragma unroll
            for (int jc = 0; jc < 6; ++jc) {
                float4 wq[4];
#pragma unroll
                for (int v = 0; v < 4; ++v)
                    wq[v] = *reinterpret_cast<const float4*>(wgt + (size_t)(v0 + v) * NJ + jc * 4);
#pragma unroll
                for (int l = 0; l < 4; ++l) {
                    const int jj = jc * 4 + l;
                    const float4 m0 = *reinterpret_cast<const float4*>(Mb + jj * 16 + 0);
                    const float4 m1 = *reinterpret_cast<const float4*>(Mb + jj * 16 + 4);
                    const float4 m2 = *reinterpret_cast<const float4*>(Mb + jj * 16 + 8);
                    const float m[12] = {m0.x, m0.y, m0.z, m0.w, m1.x, m1.y,
                                         m1.z, m1.w, m2.x, m2.y, m2.z, m2.w};
                    const float wl[4] = {f4c(wq[0], l), f4c(wq[1], l), f4c(wq[2], l), f4c(wq[3], l)};
#pragma unroll
                    for (int v = 0; v < 4; ++v)
#pragma unroll
                        for (int q = 0; q < 12; ++q) acc[v][q] += wl[v] * m[q];
                }
            }
        }

        const float* vp = verts + ((size_t)b * NV + v0) * 3;
        const float4 p0 = *reinterpret_cast<const float4*>(vp + 0);
        const float4 p1 = *reinterpret_cast<const float4*>(vp + 4);
        const float4 p2 = *reinterpret_cast<const float4*>(vp + 8);
        const float px[4] = {p0.x, p0.w, p1.z, p2.y};
        const float py[4] = {p0.y, p1.x, p1.w, p2.z};
        const float pz[4] = {p0.z, p1.y, p2.x, p2.w};

        float o[12];
#pragma unroll
        for (int v = 0; v < 4; ++v)
#pragma unroll
            for (int rr = 0; rr < 3; ++rr)
                o[v * 3 + rr] = acc[v][rr * 4 + 0] * px[v] + acc[v][rr * 4 + 1] * py[v] +
                                acc[v][rr * 4 + 2] * pz[v] + acc[v][rr * 4 + 3];

        float* op = out_verts + ((size_t)b * NV + v0) * 3;
        *reinterpret_cast<float4*>(op + 0) = make_float4(o[0], o[1], o[2],  o[3]);
        *reinterpret_cast<float4*>(op + 4) = make_float4(o[4], o[5], o[6],  o[7]);
        *reinterpret_cast<float4*>(op + 8) = make_float4(o[8], o[9], o[10], o[11]);
    } else {
        // tail (last partial thread only)
        for (int vi = 0; vi < 4; ++vi) {
            const int v = v0 + vi;
            if (v >= NV) break;
            float a[12];
#pragma unroll
            for (int q = 0; q < 12; ++q) a[q] = 0.0f;
#pragma unroll
            for (int jj = 0; jj < NJ; ++jj) {
                const float wv = WT ? wTp[(size_t)jj * WT_LD + v] : wgt[(size_t)v * NJ + jj];
#pragma unroll
                for (int q = 0; q < 12; ++q) a[q] += wv * Mb[jj * 16 + q];
            }
            const float* vp = verts + ((size_t)b * NV + v) * 3;
            const float x = vp[0], y = vp[1], z = vp[2];
            float* op = out_verts + ((size_t)b * NV + v) * 3;
            op[0] = a[0] * x + a[1] * y + a[2]  * z + a[3];
            op[1] = a[4] * x + a[5] * y + a[6]  * z + a[7];
            op[2] = a[8] * x + a[9] * y + a[10] * z + a[11];
        }
    }
}

extern "C" void kernel_launch(void* const* d_in, const int* in_sizes, int n_in,
                              void* d_out, int out_size, void* d_ws, size_t ws_size,
                              hipStream_t stream) {
    const float* rot     = (const float*)d_in[0];   // (B,J,3,3)
    const float* joints  = (const float*)d_in[1];   // (B,J,3)
    const float* verts   = (const float*)d_in[2];   // (B,V,3)
    const float* weights = (const float*)d_in[3];   // (V,J)

    float* out = (float*)d_out;
    float* posed_verts  = out;                                   // B*V*3
    float* posed_joints = out + (size_t)NB * NV * 3;             // B*J*3
    float* rel_tf       = posed_joints + (size_t)NB * NJ * 3;    // B*J*16

    const size_t WT_BYTES = (size_t)NJ * WT_LD * sizeof(float);
    const bool use_wt = (d_ws != nullptr) && (ws_size >= WT_BYTES);

    if (use_wt) {
        transpose_w<<<(NV * NJ + 255) / 256, 256, 0, stream>>>(weights, (float*)d_ws);
    }
    chain2<<<NB, 288, 0, stream>>>(rot, joints, posed_joints, rel_tf);

    const int nbx = (NV + 1023) / 1024;   // 7
    if (use_wt) {
        lbs2<true><<<dim3(nbx, NB), 256, 0, stream>>>(verts, weights, (const float*)d_ws,
                                                      rel_tf, posed_verts);
    } else {
        lbs2<false><<<dim3(nbx, NB), 256, 0, stream>>>(verts, weights, nullptr,
                                                       rel_tf, posed_verts);
    }
}

// Round 6
// 112.034 us; speedup vs baseline: 1.1499x; 1.1499x over previous
//
#include <hip/hip_runtime.h>

#define NB 256
#define NJ 24
#define NV 6890
#define VPB 256   // vertices per block, 1 per thread

// ---------------------------------------------------------------------------
// Kernel 1: kinematic chain via parallel ancestor doubling (unchanged, passed).
// One block per batch, 288 threads = 24 joints x 12 matrix elements.
// ---------------------------------------------------------------------------
__device__ __constant__ int ANC[4][NJ] = {
  {-1, 0, 0, 0, 1, 2, 3, 4, 5, 6, 7, 8, 9, 9, 9,12,13,14,16,17,18,19,20,21},
  {-1,-1,-1,-1, 0, 0, 0, 1, 2, 3, 4, 5, 6, 6, 6, 9, 9, 9,13,14,16,17,18,19},
  {-1,-1,-1,-1,-1,-1,-1,-1,-1,-1, 0, 0, 0, 0, 0, 3, 3, 3, 6, 6, 9, 9,13,14},
  {-1,-1,-1,-1,-1,-1,-1,-1,-1,-1,-1,-1,-1,-1,-1,-1,-1,-1,-1,-1,-1,-1, 0, 0}};

__global__ __launch_bounds__(288) void chain2(
    const float* __restrict__ rot,      // (B,J,3,3)
    const float* __restrict__ joints,   // (B,J,3)
    float* __restrict__ posed_joints,   // (B,J,3)
    float* __restrict__ rel_tf)         // (B,J,4,4)
{
    __shared__ float Jl[NJ * 3];
    __shared__ float MA[NJ * 12];
    __shared__ float MB[NJ * 12];
    const int b = blockIdx.x, tid = threadIdx.x;
    const int j = tid / 12, e = tid % 12, r = e >> 2, c = e & 3;
    constexpr int par[NJ] = {0,0,0,0,1,2,3,4,5,6,7,8,9,9,9,12,13,14,16,17,18,19,20,21};

    if (tid < NJ * 3) Jl[tid] = joints[(size_t)b * NJ * 3 + tid];
    __syncthreads();

    float tv;
    if (c < 3) {
        tv = rot[(size_t)b * NJ * 9 + j * 9 + r * 3 + c];
    } else {
        tv = Jl[j * 3 + r];
        if (j > 0) tv -= Jl[par[j] * 3 + r];
    }
    MA[j * 12 + e] = tv;
    __syncthreads();

#define DSTEP(SRC, DST, K)                                                 \
    do {                                                                   \
        const int a = ANC[K][j];                                           \
        float nv;                                                          \
        if (a < 0) {                                                       \
            nv = SRC[j * 12 + e];                                          \
        } else {                                                           \
            nv = SRC[a * 12 + r * 4 + 0] * SRC[j * 12 + 0 + c]            \
               + SRC[a * 12 + r * 4 + 1] * SRC[j * 12 + 4 + c]            \
               + SRC[a * 12 + r * 4 + 2] * SRC[j * 12 + 8 + c];           \
            if (c == 3) nv += SRC[a * 12 + r * 4 + 3];                    \
        }                                                                  \
        DST[j * 12 + e] = nv;                                              \
        __syncthreads();                                                   \
    } while (0)

    DSTEP(MA, MB, 0);
    DSTEP(MB, MA, 1);
    DSTEP(MA, MB, 2);
    DSTEP(MB, MA, 3);

    const float aje = MA[j * 12 + e];
    if (c == 3) {
        posed_joints[(size_t)b * NJ * 3 + j * 3 + r] = aje;
        const float tj = MA[j * 12 + r * 4 + 0] * Jl[j * 3 + 0]
                       + MA[j * 12 + r * 4 + 1] * Jl[j * 3 + 1]
                       + MA[j * 12 + r * 4 + 2] * Jl[j * 3 + 2];
        rel_tf[(size_t)b * NJ * 16 + j * 16 + e] = aje - tj;
    } else {
        rel_tf[(size_t)b * NJ * 16 + j * 16 + e] = aje;
    }
    if (tid < NJ * 4) {
        const int j2 = tid >> 2, c2 = tid & 3;
        rel_tf[(size_t)b * NJ * 16 + j2 * 16 + 12 + c2] = (c2 == 3) ? 1.0f : 0.0f;
    }
}

// ---------------------------------------------------------------------------
// Kernel 2: vertex blend v3. 1 vertex/thread. ALL global accesses coalesced
// via LDS staging; weights in stride-25 LDS rows (conflict-free); M read as
// wave-uniform ds_read_b128 broadcasts.
// ---------------------------------------------------------------------------
__global__ __launch_bounds__(VPB) void lbs3(
    const float* __restrict__ verts,    // (B,V,3)
    const float* __restrict__ wgt,      // (V,J)
    const float* __restrict__ rel_tf,   // (B,J,4,4)
    float* __restrict__ out_verts)      // (B,V,3)
{
    __shared__ float Wlds[VPB * 25];    // 25.6 KB; row stride 25 -> gcd(25,32)=1
    __shared__ float Mlds[NJ * 16];     // 1.5 KB (full 4x4s, coalesced staging)
    __shared__ float Vio[VPB * 3];      // 3 KB; verts in, then outputs out
    const int tid = threadIdx.x;
    const int b = blockIdx.y;
    const int v0 = blockIdx.x * VPB;
    const int nvalid = min(VPB, NV - v0);

    // stage M: 384 contiguous floats
    for (int i = tid; i < NJ * 16; i += VPB)
        Mlds[i] = rel_tf[(size_t)b * NJ * 16 + i];

    // stage W: nvalid*24 floats as float4 (v0*NJ*4B = blockIdx.x*24576 -> 16B ok)
    {
        const float4* wg = reinterpret_cast<const float4*>(wgt + (size_t)v0 * NJ);
        const int nf4 = nvalid * NJ / 4;          // NJ % 4 == 0
        for (int i = tid; i < nf4; i += VPB) {
            const float4 q = wg[i];
            const int f = i * 4;
            const int v = f / NJ, j = f % NJ;     // j in {0,4,...,20}: no row crossing
            float* d = &Wlds[v * 25 + j];
            d[0] = q.x; d[1] = q.y; d[2] = q.z; d[3] = q.w;
        }
    }

    // stage verts: nvalid*3 floats as float2 (base even, count even)
    {
        const float2* vg = reinterpret_cast<const float2*>(verts + ((size_t)b * NV + v0) * 3);
        const int nf2 = nvalid * 3 / 2;
        for (int i = tid; i < nf2; i += VPB) {
            const float2 q = vg[i];
            Vio[i * 2 + 0] = q.x;
            Vio[i * 2 + 1] = q.y;
        }
    }
    __syncthreads();

    float o0 = 0.0f, o1 = 0.0f, o2 = 0.0f;
    if (tid < nvalid) {
        const float x = Vio[tid * 3 + 0];
        const float y = Vio[tid * 3 + 1];
        const float z = Vio[tid * 3 + 2];

        float w[NJ];
#pragma unroll
        for (int j = 0; j < NJ; ++j) w[j] = Wlds[tid * 25 + j];  // conflict-free

        float acc[12];
#pragma unroll
        for (int q = 0; q < 12; ++q) acc[q] = 0.0f;

        const float4* M4 = reinterpret_cast<const float4*>(Mlds);
#pragma unroll 4
        for (int j = 0; j < NJ; ++j) {
            const float4 m0 = M4[j * 4 + 0];   // uniform addr -> LDS broadcast
            const float4 m1 = M4[j * 4 + 1];
            const float4 m2 = M4[j * 4 + 2];
            const float wj = w[j];
            acc[0] += wj * m0.x; acc[1]  += wj * m0.y; acc[2]  += wj * m0.z; acc[3]  += wj * m0.w;
            acc[4] += wj * m1.x; acc[5]  += wj * m1.y; acc[6]  += wj * m1.z; acc[7]  += wj * m1.w;
            acc[8] += wj * m2.x; acc[9]  += wj * m2.y; acc[10] += wj * m2.z; acc[11] += wj * m2.w;
        }

        o0 = acc[0] * x + acc[1] * y + acc[2]  * z + acc[3];
        o1 = acc[4] * x + acc[5] * y + acc[6]  * z + acc[7];
        o2 = acc[8] * x + acc[9] * y + acc[10] * z + acc[11];
    }
    __syncthreads();            // Vio's input role done
    if (tid < nvalid) {
        Vio[tid * 3 + 0] = o0;  // stride-3: gcd(3,32)=1 -> 2-way, free
        Vio[tid * 3 + 1] = o1;
        Vio[tid * 3 + 2] = o2;
    }
    __syncthreads();

    // coalesced float2 store of nvalid*3 floats
    {
        float2* og = reinterpret_cast<float2*>(out_verts + ((size_t)b * NV + v0) * 3);
        const int nf2 = nvalid * 3 / 2;
        for (int i = tid; i < nf2; i += VPB)
            og[i] = make_float2(Vio[i * 2 + 0], Vio[i * 2 + 1]);
    }
}

extern "C" void kernel_launch(void* const* d_in, const int* in_sizes, int n_in,
                              void* d_out, int out_size, void* d_ws, size_t ws_size,
                              hipStream_t stream) {
    const float* rot     = (const float*)d_in[0];   // (B,J,3,3)
    const float* joints  = (const float*)d_in[1];   // (B,J,3)
    const float* verts   = (const float*)d_in[2];   // (B,V,3)
    const float* weights = (const float*)d_in[3];   // (V,J)

    float* out = (float*)d_out;
    float* posed_verts  = out;                                   // B*V*3
    float* posed_joints = out + (size_t)NB * NV * 3;             // B*J*3
    float* rel_tf       = posed_joints + (size_t)NB * NJ * 3;    // B*J*16

    chain2<<<NB, 288, 0, stream>>>(rot, joints, posed_joints, rel_tf);

    const int nbx = (NV + VPB - 1) / VPB;   // 27
    lbs3<<<dim3(nbx, NB), VPB, 0, stream>>>(verts, weights, rel_tf, posed_verts);
}